// Round 1
// baseline (533.084 us; speedup 1.0000x reference)
//
#include <hip/hip_runtime.h>
#include <stdint.h>

// Problem constants
#define N_NODES 25000
#define N_EDGES 400000
#define OUT_ELEMS 3200000          // 25000 * 2 * 64 floats
// max total chunks: sum ceil(deg/8) <= (400000 + 7*25000)/8 = 71875
#define MAX_CHUNKS 72000

typedef __attribute__((ext_vector_type(8))) short short8;   // 8 bf16 = 4 VGPRs
typedef __attribute__((ext_vector_type(4))) float f32x4;    // MFMA accum

#define MFMA16(a, b, c) __builtin_amdgcn_mfma_f32_16x16x32_bf16((a), (b), (c), 0, 0, 0)

// fp32 -> bf16, round-to-nearest-even (weights / q path)
__device__ __forceinline__ short bf16r(float x) {
    unsigned u = __float_as_uint(x);
    u += 0x7FFFu + ((u >> 16) & 1u);
    return (short)(u >> 16);
}
// fp32 -> bf16, round-half-up (hot edge path)
__device__ __forceinline__ short bfr(float x) {
    return (short)((__float_as_uint(x) + 0x8000u) >> 16);
}

// Sum over each 16-lane group via DPP butterfly (pure VALU, no DS traffic).
#define DPP_ADD(x, ctrl) \
    ((x) + __int_as_float(__builtin_amdgcn_update_dpp(0, __float_as_int(x), (ctrl), 0xF, 0xF, true)))
__device__ __forceinline__ float red16(float x) {
    x = DPP_ADD(x, 0xB1);    // quad_perm [1,0,3,2]  (xor 1)
    x = DPP_ADD(x, 0x4E);    // quad_perm [2,3,0,1]  (xor 2)
    x = DPP_ADD(x, 0x141);   // row_half_mirror      (8-group)
    x = DPP_ADD(x, 0x140);   // row_mirror           (16-group)
    return x;
}

// order-preserving float -> uint map (monotone): max over floats == umax over maps
__device__ __forceinline__ unsigned fmap(float x) {
    const unsigned u = __float_as_uint(x);
    return ((int)u >= 0) ? (u | 0x80000000u) : ~u;
}
// fmap(-inf) = ~0xFF800000 = 0x007FFFFF  (the init value for the atomic-max buffer)
#define MAPPED_NEG_INF 0x007FFFFFu

// B fragment for cols [colbase, colbase+16) of [64 x 64] row-major fp32 W.
// B layout: n = lane&15, k = (lane>>4)*8 + j (+32 per khalf). Validated R2/R3.
__device__ __forceinline__ short8 load_bfrag(const float* __restrict__ W,
                                             int colbase, int lane, int khalf) {
    const int n = colbase + (lane & 15);
    const int k0 = khalf * 32 + ((lane >> 4) << 3);
    short8 f;
    #pragma unroll
    for (int j = 0; j < 8; ++j) f[j] = bf16r(W[(k0 + j) * 64 + n]);
    return f;
}

// A fragment from LDS tile (16 rows padded to 72 shorts = 144 B). Validated R2/R3.
__device__ __forceinline__ short8 afrag(const short* S, int lane, int khalf) {
    return *(const short8*)&S[(lane & 15) * 72 + khalf * 32 + ((lane >> 4) << 3)];
}

// ---------- init: out buffer to mapped(-inf) + zero CSR counts ----------
__global__ __launch_bounds__(256) void init_kernel(unsigned* __restrict__ out_u,
                                                   int* __restrict__ counts) {
    const int i = blockIdx.x * 256 + threadIdx.x;   // grid covers OUT_ELEMS exactly
    out_u[i] = MAPPED_NEG_INF;
    if (i < N_NODES) counts[i] = 0;
}

// ---------- CSR build ----------
__global__ __launch_bounds__(256) void hist_kernel(const int* __restrict__ dst,
                                                   int* __restrict__ counts) {
    const int i = blockIdx.x * 256 + threadIdx.x;
    if (i < N_EDGES) atomicAdd(&counts[dst[i]], 1);
}

#define BPT 98   // 256*98 = 25088 >= 25000
__global__ __launch_bounds__(256) void scan_kernel(const int* __restrict__ counts,
                                                   int* __restrict__ offsets,
                                                   int* __restrict__ cursor,
                                                   int* __restrict__ chunkoff) {
    __shared__ int pd[256];   // edge-count prefix
    __shared__ int pc[256];   // chunk-count prefix
    const int t = threadIdx.x;
    const int base = t * BPT;
    int sd = 0, sc = 0;
    for (int j = 0; j < BPT; ++j) {
        const int idx = base + j;
        if (idx < N_NODES) {
            const int d = counts[idx];
            sd += d;
            sc += (d + 7) >> 3;
        }
    }
    pd[t] = sd; pc[t] = sc;
    __syncthreads();
    for (int d = 1; d < 256; d <<= 1) {
        const int ad = (t >= d) ? pd[t - d] : 0;
        const int ac = (t >= d) ? pc[t - d] : 0;
        __syncthreads();
        pd[t] += ad; pc[t] += ac;
        __syncthreads();
    }
    int rd = (t > 0) ? pd[t - 1] : 0;
    int rc = (t > 0) ? pc[t - 1] : 0;
    for (int j = 0; j < BPT; ++j) {
        const int idx = base + j;
        if (idx < N_NODES) {
            offsets[idx]  = rd;
            cursor[idx]   = rd;
            chunkoff[idx] = rc;
            const int d = counts[idx];
            rd += d;
            rc += (d + 7) >> 3;
        }
    }
    if (t == 255) { offsets[N_NODES] = pd[255]; chunkoff[N_NODES] = pc[255]; }
}

// chunk descriptors: .x = node v, .y = base_edge | (nvalid << 24)   (nvalid in 1..8)
__global__ __launch_bounds__(256) void fill_kernel(const int* __restrict__ offsets,
                                                   const int* __restrict__ chunkoff,
                                                   int2* __restrict__ chunk_desc) {
    const int v = blockIdx.x * 256 + threadIdx.x;
    if (v < N_NODES) {
        const int off0 = offsets[v];
        const int deg  = offsets[v + 1] - off0;
        const int nch  = (deg + 7) >> 3;
        const int co   = chunkoff[v];
        for (int c = 0; c < nch; ++c) {
            int nval = deg - (c << 3);
            if (nval > 8) nval = 8;
            int2 d;
            d.x = v;
            d.y = (off0 + (c << 3)) | (nval << 24);
            chunk_desc[co + c] = d;
        }
    }
}

__global__ __launch_bounds__(256) void scatter_kernel(
    const int* __restrict__ src, const int* __restrict__ dst,
    int* __restrict__ cursor, int* __restrict__ perm, int* __restrict__ srcs) {
    const int i = blockIdx.x * 256 + threadIdx.x;
    if (i < N_EDGES) {
        const int d = dst[i];
        const int pos = atomicAdd(&cursor[d], 1);
        perm[pos] = i;
        srcs[pos] = src[i];
    }
}

// ---------- Q = h @ W_Q (MFMA) + fused weight-fragment prep (block 0) ----------
__global__ __launch_bounds__(256) void q_mfma_kernel(
    const float* __restrict__ h, const float* __restrict__ Wq,
    const float* __restrict__ Wk, const float* __restrict__ Wv,
    const float* __restrict__ Wr, float* __restrict__ Q, short8* __restrict__ fw)
{
    __shared__ short sH[64 * 72];
    const int t = threadIdx.x;
    const int lane = t & 63, w = t >> 6;
    const int wcol = w << 4;
    const int ln = lane & 15, lq = lane >> 4;
    const int base = blockIdx.x * 64;

    const short8 b0 = load_bfrag(Wq, wcol, lane, 0);
    const short8 b1 = load_bfrag(Wq, wcol, lane, 1);

    {
        const int r = t >> 2, c4 = (t & 3) << 4;
        int row = base + r; if (row > 49999) row = 49999;
        const float4* p = (const float4*)&h[row * 64 + c4];
        short tmp[16];
        #pragma unroll
        for (int i = 0; i < 4; ++i) {
            float4 x = p[i];
            tmp[4*i+0] = bf16r(x.x); tmp[4*i+1] = bf16r(x.y);
            tmp[4*i+2] = bf16r(x.z); tmp[4*i+3] = bf16r(x.w);
        }
        *(short8*)&sH[r * 72 + c4]     = *(short8*)&tmp[0];
        *(short8*)&sH[r * 72 + c4 + 8] = *(short8*)&tmp[8];
    }
    __syncthreads();

    #pragma unroll
    for (int m = 0; m < 4; ++m) {
        const short* Sm = &sH[(m << 4) * 72];
        short8 a0 = afrag(Sm, lane, 0);
        short8 a1 = afrag(Sm, lane, 1);
        f32x4 acc = {0.f, 0.f, 0.f, 0.f};
        acc = MFMA16(a0, b0, acc);
        acc = MFMA16(a1, b1, acc);
        #pragma unroll
        for (int reg = 0; reg < 4; ++reg) {
            const int row = base + (m << 4) + (lq << 2) + reg;
            if (row < 50000) Q[row * 64 + wcol + ln] = acc[reg];
        }
    }

    if (blockIdx.x == 0) {   // weight fragments for the edge kernel
        fw[(w * 6 + 0) * 64 + lane] = load_bfrag(Wk, wcol, lane, 0);
        fw[(w * 6 + 1) * 64 + lane] = load_bfrag(Wk, wcol, lane, 1);
        fw[(w * 6 + 2) * 64 + lane] = load_bfrag(Wv, wcol, lane, 0);
        fw[(w * 6 + 3) * 64 + lane] = load_bfrag(Wv, wcol, lane, 1);
        fw[(w * 6 + 4) * 64 + lane] = load_bfrag(Wr, wcol, lane, 0);
        fw[(w * 6 + 5) * 64 + lane] = load_bfrag(Wr, wcol, lane, 1);
    }
}

// ---------- edge kernel v2: one WAVE per 8-edge CHUNK, LDS-free, straight-line ----------
// Each lane builds its MFMA A-fragment directly from global memory:
//   A row = lane&15  -> edge slot (lane&15)>>1, group n = (lane&15)&1
//   A cols = khalf*32 + (lane>>4)*8 .. +7   (two 32B segments per stream)
// Cross-chunk combine via device-scope atomicMax on order-preserving uint maps.
__global__ __launch_bounds__(256, 4) void edge_chunk_kernel(
    const float* __restrict__ h, const float* __restrict__ e,
    const float* __restrict__ Q, const int* __restrict__ srcs,
    const int* __restrict__ perm, const int* __restrict__ chunkoff,
    const int2* __restrict__ chunk_desc, const short8* __restrict__ fw,
    unsigned* __restrict__ out_u)
{
    const int t = threadIdx.x;
    const int lane = t & 63;
    const int g = (blockIdx.x << 2) + (t >> 6);
    if (g >= chunkoff[N_NODES]) return;      // beyond last chunk -> idle wave

    const int2 dsc = chunk_desc[g];
    const int v    = dsc.x;
    const int base = dsc.y & 0xFFFFFF;
    const int nval = dsc.y >> 24;            // valid edges in this chunk, 1..8

    const int ln = lane & 15, lq = lane >> 4;
    const int eloc = ln >> 1, nr = ln & 1;   // this lane's A-row: edge slot + group
    const int k0 = lq << 3;                  // col base within a 32-col half

    const int elc = (eloc < nval - 1) ? eloc : (nval - 1);   // clamp (loads only)
    const int ei  = base + elc;
    const int ed  = perm[ei];
    const int s   = srcs[ei];

    // all-head resident weight fragments (24 x b128, L1/L2-hot, same for all waves)
    short8 bK0[4], bK1[4], bV0[4], bV1[4], bR0[4], bR1[4];
    #pragma unroll
    for (int hd = 0; hd < 4; ++hd) {
        bK0[hd] = fw[(hd * 6 + 0) * 64 + lane];
        bK1[hd] = fw[(hd * 6 + 1) * 64 + lane];
        bV0[hd] = fw[(hd * 6 + 2) * 64 + lane];
        bV1[hd] = fw[(hd * 6 + 3) * 64 + lane];
        bR0[hd] = fw[(hd * 6 + 4) * 64 + lane];
        bR1[hd] = fw[(hd * 6 + 5) * 64 + lane];
    }

    // direct A (relu diff) and E fragments — no LDS round trip, no wave_barrier
    const float* __restrict__ hs  = &h[((s  << 1) + nr) << 6];
    const float* __restrict__ hdp = &h[((v  << 1) + nr) << 6];
    const float* __restrict__ ep  = &e[((ed << 1) + nr) << 6];

    short8 afr[2], gfr[2];
    #pragma unroll
    for (int half = 0; half < 2; ++half) {
        const int cb = (half << 5) + k0;
        const float4 s0 = *(const float4*)&hs[cb];
        const float4 s1 = *(const float4*)&hs[cb + 4];
        const float4 d0 = *(const float4*)&hdp[cb];
        const float4 d1 = *(const float4*)&hdp[cb + 4];
        const float4 e0 = *(const float4*)&ep[cb];
        const float4 e1 = *(const float4*)&ep[cb + 4];
        short8 ta, tg;
        ta[0] = bfr(fmaxf(s0.x - d0.x, 0.f));
        ta[1] = bfr(fmaxf(s0.y - d0.y, 0.f));
        ta[2] = bfr(fmaxf(s0.z - d0.z, 0.f));
        ta[3] = bfr(fmaxf(s0.w - d0.w, 0.f));
        ta[4] = bfr(fmaxf(s1.x - d1.x, 0.f));
        ta[5] = bfr(fmaxf(s1.y - d1.y, 0.f));
        ta[6] = bfr(fmaxf(s1.z - d1.z, 0.f));
        ta[7] = bfr(fmaxf(s1.w - d1.w, 0.f));
        tg[0] = bfr(e0.x); tg[1] = bfr(e0.y); tg[2] = bfr(e0.z); tg[3] = bfr(e0.w);
        tg[4] = bfr(e1.x); tg[5] = bfr(e1.y); tg[6] = bfr(e1.z); tg[7] = bfr(e1.w);
        afr[half] = ta;
        gfr[half] = tg;
    }

    // Q rows + per-(n,head) norms (wave-invariant: one node per wave)
    float q0[4], q1[4], qn0[4], qn1[4];
    #pragma unroll
    for (int hd = 0; hd < 4; ++hd) {
        q0[hd] = Q[(v << 7) + (hd << 4) + ln];
        q1[hd] = Q[(v << 7) + 64 + (hd << 4) + ln];
        qn0[hd] = sqrtf(red16(q0[hd] * q0[hd]));
        qn1[hd] = sqrtf(red16(q1[hd] * q1[hd]));
    }

    const float NEG_INF = __uint_as_float(0xFF800000u);
    float rm0[4] = {NEG_INF, NEG_INF, NEG_INF, NEG_INF};
    float rm1[4] = {NEG_INF, NEG_INF, NEG_INF, NEG_INF};

    #pragma unroll
    for (int hd = 0; hd < 4; ++hd) {
        f32x4 aK = {0.f, 0.f, 0.f, 0.f}, aV = aK, aR = aK;
        aK = MFMA16(afr[0], bK0[hd], aK); aK = MFMA16(afr[1], bK1[hd], aK);
        aV = MFMA16(afr[0], bV0[hd], aV); aV = MFMA16(afr[1], bV1[hd], aV);
        aR = MFMA16(gfr[0], bR0[hd], aR); aR = MFMA16(gfr[1], bR1[hd], aR);

        #pragma unroll
        for (int reg = 0; reg < 4; ++reg) {
            const int rl = (lq << 2) + reg;         // C row = quad*4+reg
            const int el = rl >> 1;                 // edge slot of this C row
            const int n2 = reg & 1;                 // == rl&1
            const bool valid = el < nval;
            const float kk = aK[reg];
            const float sk = red16(kk * kk);        // ||k||^2 over head's 16 cols
            const float scale = sqrtf(sk) * (n2 ? qn1[hd] : qn0[hd]) + 1e-6f;
            const float qv = n2 ? q1[hd] : q0[hd];
            float msg = (qv * kk * scale + aR[reg]) * aV[reg];
            msg = valid ? msg : NEG_INF;
            if (n2) rm1[hd] = fmaxf(rm1[hd], msg);
            else    rm0[hd] = fmaxf(rm0[hd], msg);
        }
    }

    // max across quads (disjoint edges per quad), then one atomicMax per lane
    #pragma unroll
    for (int hd = 0; hd < 4; ++hd) {
        rm0[hd] = fmaxf(rm0[hd], __shfl_xor(rm0[hd], 16));
        rm0[hd] = fmaxf(rm0[hd], __shfl_xor(rm0[hd], 32));
        rm1[hd] = fmaxf(rm1[hd], __shfl_xor(rm1[hd], 16));
        rm1[hd] = fmaxf(rm1[hd], __shfl_xor(rm1[hd], 32));
    }
    const float o0 = (lq == 0) ? rm0[0] : (lq == 1) ? rm0[1] : (lq == 2) ? rm0[2] : rm0[3];
    const float o1 = (lq == 0) ? rm1[0] : (lq == 1) ? rm1[1] : (lq == 2) ? rm1[2] : rm1[3];
    atomicMax(&out_u[(v << 7) + lane],      fmap(o0));
    atomicMax(&out_u[(v << 7) + 64 + lane], fmap(o1));
}

// ---------- final: unmap uint -> float in place; untouched (-inf) -> 0 ----------
__global__ __launch_bounds__(256) void final_kernel(unsigned* __restrict__ io) {
    const int i = blockIdx.x * 256 + threadIdx.x;   // grid covers OUT_ELEMS/4 exactly
    uint4* p = (uint4*)io;
    uint4 m = p[i];
    unsigned a, b, c, d;
    a = (m.x & 0x80000000u) ? (m.x ^ 0x80000000u) : ~m.x;
    b = (m.y & 0x80000000u) ? (m.y ^ 0x80000000u) : ~m.y;
    c = (m.z & 0x80000000u) ? (m.z ^ 0x80000000u) : ~m.z;
    d = (m.w & 0x80000000u) ? (m.w ^ 0x80000000u) : ~m.w;
    if (a == 0xFF800000u) a = 0u;   // zero in-degree -> 0 (DGL convention)
    if (b == 0xFF800000u) b = 0u;
    if (c == 0xFF800000u) c = 0u;
    if (d == 0xFF800000u) d = 0u;
    m.x = a; m.y = b; m.z = c; m.w = d;
    p[i] = m;
}

extern "C" void kernel_launch(void* const* d_in, const int* in_sizes, int n_in,
                              void* d_out, int out_size, void* d_ws, size_t ws_size,
                              hipStream_t stream) {
    const float* h  = (const float*)d_in[0];
    const float* e  = (const float*)d_in[1];
    const float* Wq = (const float*)d_in[2];
    const float* Wk = (const float*)d_in[3];
    const float* Wv = (const float*)d_in[4];
    const float* Wr = (const float*)d_in[5];
    const int*   src = (const int*)d_in[6];
    const int*   dst = (const int*)d_in[7];
    float* out = (float*)d_out;

    // workspace layout (4B units), ~17.0 MB total
    float* Q        = (float*)d_ws;                        // 3,200,000
    int*   counts   = (int*)d_ws + 3200000;                // 25,000
    int*   offsets  = (int*)d_ws + 3225000;                // 25,001
    int*   cursor   = (int*)d_ws + 3250008;                // 25,000
    int*   perm     = (int*)d_ws + 3275008;                // 400,000
    int*   srcs     = (int*)d_ws + 3675008;                // 400,000
    short8* fw      = (short8*)((int*)d_ws + 4075008);     // 1536 x 16B = 6144 ints
    int*   chunkoff = (int*)d_ws + 4081152;                // 25,001
    int2*  chunk_desc = (int2*)((int*)d_ws + 4106154);     // 72,000 x 8B (8B-aligned)

    init_kernel<<<12500, 256, 0, stream>>>((unsigned*)out, counts);   // 12500*256 == OUT_ELEMS
    hist_kernel<<<1563, 256, 0, stream>>>(dst, counts);
    scan_kernel<<<1, 256, 0, stream>>>(counts, offsets, cursor, chunkoff);
    fill_kernel<<<98, 256, 0, stream>>>(offsets, chunkoff, chunk_desc);
    scatter_kernel<<<1563, 256, 0, stream>>>(src, dst, cursor, perm, srcs);
    q_mfma_kernel<<<782, 256, 0, stream>>>(h, Wq, Wk, Wv, Wr, Q, fw);
    // 17969 blocks * 4 waves = 71876 >= 71875 worst-case chunks; excess waves exit early
    edge_chunk_kernel<<<17969, 256, 0, stream>>>(h, e, Q, srcs, perm,
                                                 chunkoff, chunk_desc, fw, (unsigned*)out);
    final_kernel<<<3125, 256, 0, stream>>>((unsigned*)out);           // 3125*256*4 == OUT_ELEMS
}